// Round 1
// baseline (40204.239 us; speedup 1.0000x reference)
//
#include <hip/hip_runtime.h>
#include <math.h>

// ESN: B=64, T=2048, I=25, R=512, O=50, alpha=0.5
// Decomposition: 256 blocks of 512 threads. block = (g, b): b = blk&63 (batch),
// g = blk>>6 (row-slice of 128 rows). Quad {g=0..3} of a batch exchanges h each
// step through d_ws with agent-scope atomics + per-WG monotone release counter.
// W slice [128 x 512] fp32 lives in VGPRs (128/thread). Thread tile: 8 rows x
// 16 interleaved cols (c = 128r + 32q + ct). h kept in LDS in a permuted layout
// so each thread's 16 h values are 4x ds_read_b128, conflict-free.

typedef float v2f __attribute__((ext_vector_type(2)));
typedef float v4f __attribute__((ext_vector_type(4)));

#define SCOPE_AGENT __HIP_MEMORY_SCOPE_AGENT

template<int CTRL>
__device__ __forceinline__ float dpp_add(float x) {
    int y = __builtin_amdgcn_update_dpp(0, __float_as_int(x), CTRL, 0xF, 0xF, false);
    return x + __int_as_float(y);
}
// DPP ctrl: quad_perm[1,0,3,2]=0xB1, quad_perm[2,3,0,1]=0x4E,
// row_ror:4=0x124, row_ror:8=0x128, row_bcast15=0x142

__global__ void __launch_bounds__(512, 2)
esn_kernel(const float* __restrict__ x, const float* __restrict__ Win,
           const float* __restrict__ W, const float* __restrict__ Wout,
           float* __restrict__ out, float* __restrict__ Hx, int* __restrict__ cnt)
{
    const int b    = blockIdx.x & 63;
    const int g    = blockIdx.x >> 6;
    const int tid  = threadIdx.x;
    const int rt   = tid >> 5;      // row-tile 0..15 (8 rows each)
    const int ct   = tid & 31;      // col phase 0..31
    const int lane = tid & 63;
    const int wv   = tid >> 6;      // wave 0..7
    const int hw   = rt & 1;        // half-wave

    __shared__ __align__(16) float hperm[512];      // permuted h
    __shared__ __align__(16) float red[8 * 132];    // quad-reduced partials

    // init own counter to 0 (ws is poisoned 0xAA = negative as signed)
    if (tid == 0)
        __hip_atomic_store(&cnt[(b*4 + g)*16], 0, __ATOMIC_RELAXED, SCOPE_AGENT);

    // ---- W slice -> registers: Wreg[(r*4+q)*4+p] = rows (i0+2p, i0+2p+1), col 128r+32q+ct
    v2f Wreg[64];
    {
        const int i0 = g*128 + rt*8;
        #pragma unroll
        for (int r = 0; r < 4; ++r)
        #pragma unroll
        for (int q = 0; q < 4; ++q) {
            const float* wp = W + (r*128 + q*32 + ct);
            #pragma unroll
            for (int p = 0; p < 4; ++p) {
                v2f w;
                w[0] = wp[(size_t)(i0 + 2*p    ) * 512];
                w[1] = wp[(size_t)(i0 + 2*p + 1) * 512];
                Wreg[(r*4+q)*4 + p] = w;
            }
        }
    }

    // ---- Win row (meaningful for tid<128; row i = g*128+tid)
    float WinR[25];
    {
        const int ir = g*128 + (tid & 127);
        #pragma unroll
        for (int k = 0; k < 25; ++k) WinR[k] = Win[ir*25 + k];
    }

    // ---- Wout fragment: WG g owns outputs [g*13, g*13+ocnt); wave w: o = base+2w+hw
    const int obase = g*13;
    const int ocnt  = (g == 3) ? 11 : 13;
    const int oloc  = 2*wv + hw;
    const bool ovalid = (oloc < ocnt);
    const int oidx  = obase + (ovalid ? oloc : 0);
    float WoutR[16];
    #pragma unroll
    for (int r = 0; r < 4; ++r)
    #pragma unroll
    for (int q = 0; q < 4; ++q)
        WoutR[r*4+q] = ovalid ? Wout[oidx*512 + r*128 + q*32 + ct] : 0.f;

    hperm[tid] = 0.f;           // h_0 = 0
    float holdv = 0.f;          // own row's h, carried in-register (tid<128)

    const float* xrow = x   + (size_t)b * 2048 * 25;
    float*       orow = out + (size_t)b * 2048 * 50;
    float*       HxB  = Hx  + (size_t)b * 512;          // + par*64*512 + c
    int* mycnt = &cnt[(b*4 + g)*16];
    const int src = wv >> 1;                            // slice this wave re-reads
    int* scnt  = &cnt[(b*4 + src)*16];

    __syncthreads();

    for (int t = 0; t < 2048; ++t) {
        // uniform x_t -> scalar loads
        float xs[25];
        #pragma unroll
        for (int k = 0; k < 25; ++k) xs[k] = xrow[t*25 + k];

        // ---- matvec on h_t (in hperm) + output-projection partial (for t-1)
        v2f acc0 = {0.f,0.f}, acc1 = {0.f,0.f}, acc2 = {0.f,0.f}, acc3 = {0.f,0.f};
        float op = 0.f;
        #pragma unroll
        for (int r = 0; r < 4; ++r) {
            v4f hv = *(const v4f*)&hperm[r*128 + ct*4];
            #pragma unroll
            for (int q = 0; q < 4; ++q) {
                const float hs = hv[q];
                op = fmaf(WoutR[r*4+q], hs, op);
                v2f hh = {hs, hs};
                acc0 = __builtin_elementwise_fma(Wreg[(r*4+q)*4+0], hh, acc0);
                acc1 = __builtin_elementwise_fma(Wreg[(r*4+q)*4+1], hh, acc1);
                acc2 = __builtin_elementwise_fma(Wreg[(r*4+q)*4+2], hh, acc2);
                acc3 = __builtin_elementwise_fma(Wreg[(r*4+q)*4+3], hh, acc3);
            }
        }

        // out[b][t-1][o] = Wout . h_t   (half-wave reduce, lanes 31/63 store)
        op = dpp_add<0xB1>(op);  op = dpp_add<0x4E>(op);
        op = dpp_add<0x124>(op); op = dpp_add<0x128>(op);
        op = dpp_add<0x142>(op);
        if (t > 0 && ovalid && ((lane & 31) == 31))
            orow[(size_t)(t-1)*50 + oidx] = op;

        // input projection (independent of reduction -> before B1)
        float u = 0.f;
        if (tid < 128) {
            #pragma unroll
            for (int k = 0; k < 25; ++k) u = fmaf(WinR[k], xs[k], u);
        }

        // ---- quad reduce across ct (2 DPP stages), writers ct%4==0 -> red
        float ar[8] = {acc0[0],acc0[1],acc1[0],acc1[1],acc2[0],acc2[1],acc3[0],acc3[1]};
        #pragma unroll
        for (int j = 0; j < 8; ++j) {
            ar[j] = dpp_add<0xB1>(ar[j]);
            ar[j] = dpp_add<0x4E>(ar[j]);
        }
        if ((ct & 3) == 0) {
            const int base = (ct >> 2)*132 + rt*8;
            v4f lo = { ar[0], ar[1], ar[2], ar[3] };
            v4f hi = { ar[4], ar[5], ar[6], ar[7] };
            *(v4f*)&red[base]     = lo;
            *(v4f*)&red[base + 4] = hi;
        }
        __syncthreads();   // B1

        // ---- finalize row i = g*128+tid, publish h_{t+1} slice
        if (tid < 128) {
            float y = 0.f;
            #pragma unroll
            for (int cg = 0; cg < 8; ++cg) y += red[cg*132 + tid];
            const float z  = u + y;
            const float e  = __expf(2.f * z);
            const float th = 1.f - 2.f * __builtin_amdgcn_rcpf(e + 1.f);  // tanh(z)
            holdv = 0.5f * holdv + 0.5f * th;
            __hip_atomic_store(&HxB[((t+1)&1)*64*512 + g*128 + tid], holdv,
                               __ATOMIC_RELAXED, SCOPE_AGENT);
            __hip_atomic_fetch_add(mycnt, 1, __ATOMIC_RELEASE, SCOPE_AGENT);
        }

        // ---- wait for slice `src` of step t+1, then rebuild hperm
        const int target = 128*(t+1);
        if (lane == 0) {
            while (__hip_atomic_load(scnt, __ATOMIC_RELAXED, SCOPE_AGENT) < target) {}
        }
        __builtin_amdgcn_fence(__ATOMIC_ACQUIRE, "agent");
        {
            const float hv = __hip_atomic_load(&HxB[((t+1)&1)*64*512 + tid],
                                               __ATOMIC_RELAXED, SCOPE_AGENT);
            // perm(c): idx = (c>>7)*128 + (c&31)*4 + ((c>>5)&3)
            hperm[(tid>>7)*128 + (tid&31)*4 + ((tid>>5)&3)] = hv;
        }
        __syncthreads();   // B2
    }

    // epilogue: out[b][2047] from h_2048 (now in hperm)
    {
        float op = 0.f;
        #pragma unroll
        for (int r = 0; r < 4; ++r) {
            v4f hv = *(const v4f*)&hperm[r*128 + ct*4];
            #pragma unroll
            for (int q = 0; q < 4; ++q) op = fmaf(WoutR[r*4+q], hv[q], op);
        }
        op = dpp_add<0xB1>(op);  op = dpp_add<0x4E>(op);
        op = dpp_add<0x124>(op); op = dpp_add<0x128>(op);
        op = dpp_add<0x142>(op);
        if (ovalid && ((lane & 31) == 31))
            orow[(size_t)2047*50 + oidx] = op;
    }
}

extern "C" void kernel_launch(void* const* d_in, const int* in_sizes, int n_in,
                              void* d_out, int out_size, void* d_ws, size_t ws_size,
                              hipStream_t stream)
{
    (void)in_sizes; (void)n_in; (void)out_size; (void)ws_size;
    const float* x    = (const float*)d_in[0];
    const float* Win  = (const float*)d_in[1];
    const float* W    = (const float*)d_in[2];
    const float* Wout = (const float*)d_in[3];
    float* out = (float*)d_out;
    float* Hx  = (float*)d_ws;                                   // [2][64][512] f32
    int*   cnt = (int*)((char*)d_ws + 2*64*512*sizeof(float));   // [64][4] stride 16
    esn_kernel<<<dim3(256), dim3(512), 0, stream>>>(x, Win, W, Wout, out, Hx, cnt);
}

// Round 2
// 39479.047 us; speedup vs baseline: 1.0184x; 1.0184x over previous
//
#include <hip/hip_runtime.h>
#include <math.h>

// ESN: B=64, T=2048, I=25, R=512, O=50, alpha=0.5
// 256 blocks x 512 threads; block=(g,b): b=blk&63, g=blk>>6 owns rows
// [g*128,(g+1)*128). W slice [128x512] fp32 in regs (128/thread, may land in
// AGPRs - unified file, VALU reads them directly). Per step the quad exchanges
// h via d_ws: per-WAVE release fetch_add (2 producer waves/block -> target
// 2*(t+1)) after agent-scope Hx stores; remote waves spin + acquire + reload.
// Own slice short-circuits through LDS. u_{t+1} computed under the spin.

typedef float v2f __attribute__((ext_vector_type(2)));
typedef float v4f __attribute__((ext_vector_type(4)));

#define SCOPE_AGENT __HIP_MEMORY_SCOPE_AGENT

template<int CTRL>
__device__ __forceinline__ float dpp_add(float x) {
    int y = __builtin_amdgcn_update_dpp(0, __float_as_int(x), CTRL, 0xF, 0xF, false);
    return x + __int_as_float(y);
}
// 0xB1 quad_perm[1,0,3,2], 0x4E quad_perm[2,3,0,1], 0x124 row_ror:4,
// 0x128 row_ror:8, 0x142 row_bcast15

__global__ void __launch_bounds__(512, 2)
esn_kernel(const float* __restrict__ x, const float* __restrict__ Win,
           const float* __restrict__ W, const float* __restrict__ Wout,
           float* __restrict__ out, float* __restrict__ Hx, int* __restrict__ cnt)
{
    const int b    = blockIdx.x & 63;
    const int g    = blockIdx.x >> 6;
    const int tid  = threadIdx.x;
    const int rt   = tid >> 5;      // row-tile 0..15
    const int ct   = tid & 31;      // col phase
    const int lane = tid & 63;
    const int wv   = tid >> 6;      // wave 0..7
    const int hw   = rt & 1;

    __shared__ __align__(16) float hperm[512];
    __shared__ __align__(16) float red[8 * 132];

    if (tid == 0)
        __hip_atomic_store(&cnt[(b*4 + g)*16], 0, __ATOMIC_RELAXED, SCOPE_AGENT);

    // ---- W slice -> registers
    v2f Wreg[64];
    {
        const int i0 = g*128 + rt*8;
        #pragma unroll
        for (int r = 0; r < 4; ++r)
        #pragma unroll
        for (int q = 0; q < 4; ++q) {
            const float* wp = W + (r*128 + q*32 + ct);
            #pragma unroll
            for (int p = 0; p < 4; ++p) {
                v2f w;
                w[0] = wp[(size_t)(i0 + 2*p    ) * 512];
                w[1] = wp[(size_t)(i0 + 2*p + 1) * 512];
                Wreg[(r*4+q)*4 + p] = w;
            }
        }
    }

    // ---- Win row (used by tid<128; row i = g*128+tid)
    float WinR[25];
    {
        const int ir = g*128 + (tid & 127);
        #pragma unroll
        for (int k = 0; k < 25; ++k) WinR[k] = Win[ir*25 + k];
    }

    // ---- Wout fragment
    const int obase = g*13;
    const int ocnt  = (g == 3) ? 11 : 13;
    const int oloc  = 2*wv + hw;
    const bool ovalid = (oloc < ocnt);
    const int oidx  = obase + (ovalid ? oloc : 0);
    float WoutR[16];
    #pragma unroll
    for (int r = 0; r < 4; ++r)
    #pragma unroll
    for (int q = 0; q < 4; ++q)
        WoutR[r*4+q] = ovalid ? Wout[oidx*512 + r*128 + q*32 + ct] : 0.f;

    hperm[tid] = 0.f;
    float holdv = 0.f;

    const float* xrow = x   + (size_t)b * 2048 * 25;
    float*       orow = out + (size_t)b * 2048 * 50;
    float*       HxB  = Hx  + (size_t)b * 512;
    int* mycnt = &cnt[(b*4 + g)*16];
    const int src = wv >> 1;                 // slice this wave reads/spins on
    int* scnt  = &cnt[(b*4 + src)*16];
    const bool remote = (src != g);          // whole wave is remote or local

    // u for t=0 (wave-uniform x -> scalar loads)
    float u = 0.f;
    #pragma unroll
    for (int k = 0; k < 25; ++k) u = fmaf(WinR[k], xrow[k], u);

    __syncthreads();

    for (int t = 0; t < 2048; ++t) {
        // ---- matvec on h_t + output-projection partial (emitted for t-1)
        v2f acc0 = {0.f,0.f}, acc1 = {0.f,0.f}, acc2 = {0.f,0.f}, acc3 = {0.f,0.f};
        float op = 0.f;
        #pragma unroll
        for (int r = 0; r < 4; ++r) {
            v4f hv = *(const v4f*)&hperm[r*128 + ct*4];
            #pragma unroll
            for (int q = 0; q < 4; ++q) {
                const float hs = hv[q];
                op = fmaf(WoutR[r*4+q], hs, op);
                v2f hh = {hs, hs};
                acc0 = __builtin_elementwise_fma(Wreg[(r*4+q)*4+0], hh, acc0);
                acc1 = __builtin_elementwise_fma(Wreg[(r*4+q)*4+1], hh, acc1);
                acc2 = __builtin_elementwise_fma(Wreg[(r*4+q)*4+2], hh, acc2);
                acc3 = __builtin_elementwise_fma(Wreg[(r*4+q)*4+3], hh, acc3);
            }
        }

        op = dpp_add<0xB1>(op);  op = dpp_add<0x4E>(op);
        op = dpp_add<0x124>(op); op = dpp_add<0x128>(op);
        op = dpp_add<0x142>(op);
        if (t > 0 && ovalid && ((lane & 31) == 31))
            orow[(size_t)(t-1)*50 + oidx] = op;

        // ---- quad reduce across ct
        float ar[8] = {acc0[0],acc0[1],acc1[0],acc1[1],acc2[0],acc2[1],acc3[0],acc3[1]};
        #pragma unroll
        for (int j = 0; j < 8; ++j) {
            ar[j] = dpp_add<0xB1>(ar[j]);
            ar[j] = dpp_add<0x4E>(ar[j]);
        }
        if ((ct & 3) == 0) {
            const int base = (ct >> 2)*132 + rt*8;
            *(v4f*)&red[base]     = (v4f){ ar[0], ar[1], ar[2], ar[3] };
            *(v4f*)&red[base + 4] = (v4f){ ar[4], ar[5], ar[6], ar[7] };
        }
        __syncthreads();   // B1

        // ---- finalize rows, publish h_{t+1}; ONE release add per producer wave
        if (tid < 128) {
            float y = 0.f;
            #pragma unroll
            for (int cg = 0; cg < 8; ++cg) y += red[cg*132 + tid];
            const float z  = u + y;
            const float e  = __expf(2.f * z);
            const float th = 1.f - 2.f * __builtin_amdgcn_rcpf(e + 1.f);  // tanh
            holdv = 0.5f * holdv + 0.5f * th;
            const int c = g*128 + tid;
            hperm[(c>>7)*128 + (c&31)*4 + ((c>>5)&3)] = holdv;   // own slice via LDS
            __hip_atomic_store(&HxB[((t+1)&1)*64*512 + c], holdv,
                               __ATOMIC_RELAXED, SCOPE_AGENT);
            if (lane == 0)   // lane0 of waves 0 and 1: release orders this wave's stores
                __hip_atomic_fetch_add(mycnt, 1, __ATOMIC_RELEASE, SCOPE_AGENT);
        }

        // ---- overlap: u_{t+1} under the spin (scalar x loads + 25 FMAs)
        {
            const int tt = (t < 2047) ? t + 1 : 2047;
            float un = 0.f;
            #pragma unroll
            for (int k = 0; k < 25; ++k) un = fmaf(WinR[k], xrow[tt*25 + k], un);
            u = un;
        }

        // ---- wait for remote slice of step t+1, reload
        const int target = 2*(t+1);
        if (remote && lane == 0) {
            while (__hip_atomic_load(scnt, __ATOMIC_RELAXED, SCOPE_AGENT) < target) {}
        }
        __builtin_amdgcn_fence(__ATOMIC_ACQUIRE, "agent");
        if (remote) {
            const float hv = __hip_atomic_load(&HxB[((t+1)&1)*64*512 + tid],
                                               __ATOMIC_RELAXED, SCOPE_AGENT);
            hperm[(tid>>7)*128 + (tid&31)*4 + ((tid>>5)&3)] = hv;
        }
        __syncthreads();   // B2
    }

    // epilogue: out[b][2047] from h_2048
    {
        float op = 0.f;
        #pragma unroll
        for (int r = 0; r < 4; ++r) {
            v4f hv = *(const v4f*)&hperm[r*128 + ct*4];
            #pragma unroll
            for (int q = 0; q < 4; ++q) op = fmaf(WoutR[r*4+q], hv[q], op);
        }
        op = dpp_add<0xB1>(op);  op = dpp_add<0x4E>(op);
        op = dpp_add<0x124>(op); op = dpp_add<0x128>(op);
        op = dpp_add<0x142>(op);
        if (ovalid && ((lane & 31) == 31))
            orow[(size_t)2047*50 + oidx] = op;
    }
}

extern "C" void kernel_launch(void* const* d_in, const int* in_sizes, int n_in,
                              void* d_out, int out_size, void* d_ws, size_t ws_size,
                              hipStream_t stream)
{
    (void)in_sizes; (void)n_in; (void)out_size; (void)ws_size;
    const float* x    = (const float*)d_in[0];
    const float* Win  = (const float*)d_in[1];
    const float* W    = (const float*)d_in[2];
    const float* Wout = (const float*)d_in[3];
    float* out = (float*)d_out;
    float* Hx  = (float*)d_ws;                                   // [2][64][512] f32
    int*   cnt = (int*)((char*)d_ws + 2*64*512*sizeof(float));   // [64][4] stride 16
    esn_kernel<<<dim3(256), dim3(512), 0, stream>>>(x, Win, W, Wout, out, Hx, cnt);
}

// Round 4
// 5232.879 us; speedup vs baseline: 7.6830x; 7.5444x over previous
//
#include <hip/hip_runtime.h>
#include <math.h>

// ESN: B=64, T=2048, I=25, R=512, O=50, alpha=0.5
// 256 blocks x 512 threads; block=(g,b): b=blk&63, g=blk>>6 owns rows
// [g*128,(g+1)*128). W slice [128x512] fp32 in regs.
// Sync protocol (NO fences, NO RMW, NO buffer_inv):
//  producer wave (tid<128): Hx stores with explicit `sc0 sc1` (write-through,
//  vmcnt-ack = IC visibility, proven by R1/R2), per-wave s_waitcnt vmcnt(0),
//  lane0 stores per-wave flag=t+1 (sc0 sc1).
//  consumer = wave 0 only: lanes 0..5 spin on the 6 remote flags with
//  `sc0 sc1` loads (bypass L1+L2 -> always fresh; R3 failed because relaxed
//  agent loads hit stale local-L2 lines), then 6 coherent loads/lane for the
//  384 remote h values -> hperm. Other waves skip to B2.

typedef float v2f __attribute__((ext_vector_type(2)));
typedef float v4f __attribute__((ext_vector_type(4)));

__device__ __forceinline__ void store_coh(float* p, float v) {
    asm volatile("global_store_dword %0, %1, off sc0 sc1" :: "v"(p), "v"(v) : "memory");
}
__device__ __forceinline__ void store_coh_i(int* p, int v) {
    asm volatile("global_store_dword %0, %1, off sc0 sc1" :: "v"(p), "v"(v) : "memory");
}
__device__ __forceinline__ float load_coh(const float* p) {
    float r;
    asm volatile("global_load_dword %0, %1, off sc0 sc1\n\ts_waitcnt vmcnt(0)"
                 : "=v"(r) : "v"(p) : "memory");
    return r;
}
__device__ __forceinline__ int load_coh_i(const int* p) {
    int r;
    asm volatile("global_load_dword %0, %1, off sc0 sc1\n\ts_waitcnt vmcnt(0)"
                 : "=v"(r) : "v"(p) : "memory");
    return r;
}

template<int CTRL>
__device__ __forceinline__ float dpp_add(float x) {
    int y = __builtin_amdgcn_update_dpp(0, __float_as_int(x), CTRL, 0xF, 0xF, false);
    return x + __int_as_float(y);
}
// 0xB1 quad_perm[1,0,3,2], 0x4E quad_perm[2,3,0,1], 0x124 row_ror:4,
// 0x128 row_ror:8, 0x142 row_bcast15

__global__ void __launch_bounds__(512, 2)
esn_kernel(const float* __restrict__ x, const float* __restrict__ Win,
           const float* __restrict__ W, const float* __restrict__ Wout,
           float* __restrict__ out, float* __restrict__ Hx, int* __restrict__ flg)
{
    const int b    = blockIdx.x & 63;
    const int g    = blockIdx.x >> 6;
    const int tid  = threadIdx.x;
    const int rt   = tid >> 5;      // row-tile 0..15
    const int ct   = tid & 31;      // col phase
    const int lane = tid & 63;
    const int wv   = tid >> 6;      // wave 0..7
    const int hw   = rt & 1;

    __shared__ __align__(16) float hperm[512];
    __shared__ __align__(16) float red[8 * 132];

    // ---- W slice -> registers
    v2f Wreg[64];
    {
        const int i0 = g*128 + rt*8;
        #pragma unroll
        for (int r = 0; r < 4; ++r)
        #pragma unroll
        for (int q = 0; q < 4; ++q) {
            const float* wp = W + (r*128 + q*32 + ct);
            #pragma unroll
            for (int p = 0; p < 4; ++p) {
                v2f w;
                w[0] = wp[(size_t)(i0 + 2*p    ) * 512];
                w[1] = wp[(size_t)(i0 + 2*p + 1) * 512];
                Wreg[(r*4+q)*4 + p] = w;
            }
        }
    }

    // ---- Win row (used by tid<128; row i = g*128+tid)
    float WinR[25];
    {
        const int ir = g*128 + (tid & 127);
        #pragma unroll
        for (int k = 0; k < 25; ++k) WinR[k] = Win[ir*25 + k];
    }

    // ---- Wout fragment
    const int obase = g*13;
    const int ocnt  = (g == 3) ? 11 : 13;
    const int oloc  = 2*wv + hw;
    const bool ovalid = (oloc < ocnt);
    const int oidx  = obase + (ovalid ? oloc : 0);
    float WoutR[16];
    #pragma unroll
    for (int r = 0; r < 4; ++r)
    #pragma unroll
    for (int q = 0; q < 4; ++q)
        WoutR[r*4+q] = ovalid ? Wout[oidx*512 + r*128 + q*32 + ct] : 0.f;

    hperm[tid] = 0.f;
    float holdv = 0.f;

    const float* xrow = x   + (size_t)b * 2048 * 25;
    float*       orow = out + (size_t)b * 2048 * 50;
    float*       HxB  = Hx  + (size_t)b * 512;
    // flag layout: [64 batches][4 slices][2 waves], 128 B apart
    int* myflg = &flg[((b*4 + g)*2 + wv)*32];

    // comm-wave (wave 0) remote descriptors: 3 remote slices, 2 flags each
    const int rs_lane = (g + 1 + (lane < 6 ? (lane >> 1) : 0)) & 3;  // slice for my spin lane
    int* sflg = &flg[((b*4 + rs_lane)*2 + (lane & 1))*32];

    // u for t=0 (wave-uniform x -> scalar loads)
    float u = 0.f;
    #pragma unroll
    for (int k = 0; k < 25; ++k) u = fmaf(WinR[k], xrow[k], u);

    __syncthreads();

    for (int t = 0; t < 2048; ++t) {
        // ---- matvec on h_t + output-projection partial (emitted for t-1)
        v2f acc0 = {0.f,0.f}, acc1 = {0.f,0.f}, acc2 = {0.f,0.f}, acc3 = {0.f,0.f};
        float op = 0.f;
        #pragma unroll
        for (int r = 0; r < 4; ++r) {
            v4f hv = *(const v4f*)&hperm[r*128 + ct*4];
            #pragma unroll
            for (int q = 0; q < 4; ++q) {
                const float hs = hv[q];
                op = fmaf(WoutR[r*4+q], hs, op);
                v2f hh = {hs, hs};
                acc0 = __builtin_elementwise_fma(Wreg[(r*4+q)*4+0], hh, acc0);
                acc1 = __builtin_elementwise_fma(Wreg[(r*4+q)*4+1], hh, acc1);
                acc2 = __builtin_elementwise_fma(Wreg[(r*4+q)*4+2], hh, acc2);
                acc3 = __builtin_elementwise_fma(Wreg[(r*4+q)*4+3], hh, acc3);
            }
        }

        op = dpp_add<0xB1>(op);  op = dpp_add<0x4E>(op);
        op = dpp_add<0x124>(op); op = dpp_add<0x128>(op);
        op = dpp_add<0x142>(op);
        if (t > 0 && ovalid && ((lane & 31) == 31))
            orow[(size_t)(t-1)*50 + oidx] = op;

        // ---- quad reduce across ct
        float ar[8] = {acc0[0],acc0[1],acc1[0],acc1[1],acc2[0],acc2[1],acc3[0],acc3[1]};
        #pragma unroll
        for (int j = 0; j < 8; ++j) {
            ar[j] = dpp_add<0xB1>(ar[j]);
            ar[j] = dpp_add<0x4E>(ar[j]);
        }
        if ((ct & 3) == 0) {
            const int base = (ct >> 2)*132 + rt*8;
            *(v4f*)&red[base]     = (v4f){ ar[0], ar[1], ar[2], ar[3] };
            *(v4f*)&red[base + 4] = (v4f){ ar[4], ar[5], ar[6], ar[7] };
        }
        __syncthreads();   // B1

        // ---- producer waves (0,1): finalize rows, publish h_{t+1} + per-wave flag
        if (tid < 128) {
            float y = 0.f;
            #pragma unroll
            for (int cg = 0; cg < 8; ++cg) y += red[cg*132 + tid];
            const float z  = u + y;
            const float e  = __expf(2.f * z);
            const float th = 1.f - 2.f * __builtin_amdgcn_rcpf(e + 1.f);  // tanh
            holdv = 0.5f * holdv + 0.5f * th;
            const int c = g*128 + tid;
            hperm[(c>>7)*128 + (c&31)*4 + ((c>>5)&3)] = holdv;   // own slice via LDS
            store_coh(&HxB[((t+1)&1)*64*512 + c], holdv);
            asm volatile("s_waitcnt vmcnt(0)" ::: "memory");      // wave-level release
            if (lane == 0) store_coh_i(myflg, t + 1);
        }

        // ---- overlap: u_{t+1} (scalar x loads hide under flag propagation)
        {
            const int tt = (t < 2047) ? t + 1 : 2047;
            float un = 0.f;
            #pragma unroll
            for (int k = 0; k < 25; ++k) un = fmaf(WinR[k], xrow[tt*25 + k], un);
            u = un;
        }

        // ---- comm wave: spin on 6 remote flags, pull 384 remote h values
        if (wv == 0) {
            if (lane < 6) {
                while (load_coh_i(sflg) < t + 1) {}
            }
            const float* src = &HxB[((t+1)&1)*64*512];
            #pragma unroll
            for (int j = 0; j < 3; ++j) {
                const int s = (g + 1 + j) & 3;
                #pragma unroll
                for (int h2 = 0; h2 < 2; ++h2) {
                    const int c = s*128 + h2*64 + lane;
                    const float hv = load_coh(&src[c]);
                    hperm[(c>>7)*128 + (c&31)*4 + ((c>>5)&3)] = hv;
                }
            }
        }
        __syncthreads();   // B2
    }

    // epilogue: out[b][2047] from h_2048
    {
        float op = 0.f;
        #pragma unroll
        for (int r = 0; r < 4; ++r) {
            v4f hv = *(const v4f*)&hperm[r*128 + ct*4];
            #pragma unroll
            for (int q = 0; q < 4; ++q) op = fmaf(WoutR[r*4+q], hv[q], op);
        }
        op = dpp_add<0xB1>(op);  op = dpp_add<0x4E>(op);
        op = dpp_add<0x124>(op); op = dpp_add<0x128>(op);
        op = dpp_add<0x142>(op);
        if (ovalid && ((lane & 31) == 31))
            orow[(size_t)2047*50 + oidx] = op;
    }
}

extern "C" void kernel_launch(void* const* d_in, const int* in_sizes, int n_in,
                              void* d_out, int out_size, void* d_ws, size_t ws_size,
                              hipStream_t stream)
{
    (void)in_sizes; (void)n_in; (void)out_size; (void)ws_size;
    const float* x    = (const float*)d_in[0];
    const float* Win  = (const float*)d_in[1];
    const float* W    = (const float*)d_in[2];
    const float* Wout = (const float*)d_in[3];
    float* out = (float*)d_out;
    float* Hx  = (float*)d_ws;                                   // [2][64][512] f32
    int*   flg = (int*)((char*)d_ws + 2*64*512*sizeof(float));   // [64][4][2] stride 32
    esn_kernel<<<dim3(256), dim3(512), 0, stream>>>(x, Win, W, Wout, out, Hx, flg);
}

// Round 5
// 3991.251 us; speedup vs baseline: 10.0731x; 1.3111x over previous
//
#include <hip/hip_runtime.h>
#include <math.h>

// ESN: B=64, T=2048, I=25, R=512, O=50, alpha=0.5
// 256 blocks x 512 threads; block=(g,b): b=blk&63, g=blk>>6 owns rows
// [g*128,(g+1)*128). W slice [128x512] fp32 in regs.
// R5 protocol: SEQLOCK TAGS, no flags, no fences, no producer drain.
//  - h stored as {float h, int tag=t+1} dwordx2 (8B aligned = single-copy
//    atomic) with sc0 sc1 (coherent at IC; R3 proved plain loads hit stale L2,
//    R4 proved sc0sc1 loads work).
//  - producers: lanes ct in [16,24) of each 32-lane group finalize rows
//    i0+(ct&7) after a FULL in-wave DPP reduction (row_bcast15 puts the
//    32-lane total in lanes 16..31) -> B1 and the red[] LDS round trip are
//    gone. One barrier per step; hperm parity-double-buffered.
//  - consumer (wave 0): ONE asm block issues 3x global_load_dwordx4 (one per
//    remote slice) + single vmcnt(0) (R4 bug: per-load waits serialized 6 IC
//    round trips). Stale tags retried per-lane.
// Skew bound: A stores h_{t+2} only after A's B2 of step t+1, which needs A
// fetched tags t+1 from B/C/D, which needs their B2 of step t, which needs
// they fetched tag t (h_t) -- so h_t's slot is dead before h_{t+2} lands.

typedef float v2f __attribute__((ext_vector_type(2)));
typedef float v4f __attribute__((ext_vector_type(4)));

template<int CTRL>
__device__ __forceinline__ float dpp_add(float x) {
    int y = __builtin_amdgcn_update_dpp(0, __float_as_int(x), CTRL, 0xF, 0xF, false);
    return x + __int_as_float(y);
}
// 0xB1 quad_perm[1,0,3,2], 0x4E quad_perm[2,3,0,1], 0x124 row_ror:4,
// 0x128 row_ror:8, 0x142 row_bcast15

__device__ __forceinline__ void store_coh8(float* p, float h, int tag) {
    v2f v; v[0] = h; v[1] = __int_as_float(tag);
    asm volatile("global_store_dwordx2 %0, %1, off sc0 sc1"
                 :: "v"(p), "v"(v) : "memory");
}
__device__ __forceinline__ void load3_coh16(const float* p0, const float* p1,
                                            const float* p2, v4f& a, v4f& b, v4f& c) {
    asm volatile("global_load_dwordx4 %0, %3, off sc0 sc1\n\t"
                 "global_load_dwordx4 %1, %4, off sc0 sc1\n\t"
                 "global_load_dwordx4 %2, %5, off sc0 sc1\n\t"
                 "s_waitcnt vmcnt(0)"
                 : "=&v"(a), "=&v"(b), "=&v"(c)
                 : "v"(p0), "v"(p1), "v"(p2) : "memory");
}
__device__ __forceinline__ v4f load_coh16(const float* p) {
    v4f r;
    asm volatile("global_load_dwordx4 %0, %1, off sc0 sc1\n\ts_waitcnt vmcnt(0)"
                 : "=&v"(r) : "v"(p) : "memory");
    return r;
}

__device__ __forceinline__ int permidx(int c) {
    return (c >> 7) * 128 + (c & 31) * 4 + ((c >> 5) & 3);
}

__global__ void __launch_bounds__(512, 2)
esn_kernel(const float* __restrict__ x, const float* __restrict__ Win,
           const float* __restrict__ W, const float* __restrict__ Wout,
           float* __restrict__ out, float* __restrict__ Hf)
{
    const int b    = blockIdx.x & 63;
    const int g    = blockIdx.x >> 6;
    const int tid  = threadIdx.x;
    const int rt   = tid >> 5;      // row-tile 0..15 (8 rows each)
    const int ct   = tid & 31;      // col phase
    const int lane = tid & 63;
    const int wv   = tid >> 6;      // wave 0..7
    const int hw   = rt & 1;

    __shared__ __align__(16) float hperm[2][512];

    // ---- W slice -> registers
    v2f Wreg[64];
    {
        const int i0 = g*128 + rt*8;
        #pragma unroll
        for (int r = 0; r < 4; ++r)
        #pragma unroll
        for (int q = 0; q < 4; ++q) {
            const float* wp = W + (r*128 + q*32 + ct);
            #pragma unroll
            for (int p = 0; p < 4; ++p) {
                v2f w;
                w[0] = wp[(size_t)(i0 + 2*p    ) * 512];
                w[1] = wp[(size_t)(i0 + 2*p + 1) * 512];
                Wreg[(r*4+q)*4 + p] = w;
            }
        }
    }

    // ---- Win row for this lane's finalize row i0+(ct&7)
    const int myrow = g*128 + rt*8 + (ct & 7);
    float WinR[25];
    #pragma unroll
    for (int k = 0; k < 25; ++k) WinR[k] = Win[myrow*25 + k];

    // ---- Wout fragment
    const int obase = g*13;
    const int ocnt  = (g == 3) ? 11 : 13;
    const int oloc  = 2*wv + hw;
    const bool ovalid = (oloc < ocnt);
    const int oidx  = obase + (ovalid ? oloc : 0);
    float WoutR[16];
    #pragma unroll
    for (int r = 0; r < 4; ++r)
    #pragma unroll
    for (int q = 0; q < 4; ++q)
        WoutR[r*4+q] = ovalid ? Wout[oidx*512 + r*128 + q*32 + ct] : 0.f;

    hperm[0][tid] = 0.f;        // h_0 = 0
    float holdv = 0.f;          // this lane's row h (lanes ct in [16,24))
    const bool fin = (ct >= 16) & (ct < 24);

    const float* xrow = x   + (size_t)b * 2048 * 25;
    float*       orow = out + (size_t)b * 2048 * 50;
    // tagged state: Hf[par][64][512] pairs -> float offset ((par*64+b)*512+c)*2
    float* HfB0 = Hf + (size_t)b * 1024;              // par 0
    const int s0 = (g+1)&3, s1 = (g+2)&3, s2 = (g+3)&3;

    __syncthreads();

    for (int t = 0; t < 2048; ++t) {
        const int par  = t & 1;
        const int npar = par ^ 1;
        const int want = t + 1;
        float* HfN = HfB0 + (size_t)npar * 64 * 1024;

        // ---- matvec on h_t + output-projection partial
        v2f acc0 = {0.f,0.f}, acc1 = {0.f,0.f}, acc2 = {0.f,0.f}, acc3 = {0.f,0.f};
        float op = 0.f;
        #pragma unroll
        for (int r = 0; r < 4; ++r) {
            v4f hv = *(const v4f*)&hperm[par][r*128 + ct*4];
            #pragma unroll
            for (int q = 0; q < 4; ++q) {
                const float hs = hv[q];
                op = fmaf(WoutR[r*4+q], hs, op);
                v2f hh = {hs, hs};
                acc0 = __builtin_elementwise_fma(Wreg[(r*4+q)*4+0], hh, acc0);
                acc1 = __builtin_elementwise_fma(Wreg[(r*4+q)*4+1], hh, acc1);
                acc2 = __builtin_elementwise_fma(Wreg[(r*4+q)*4+2], hh, acc2);
                acc3 = __builtin_elementwise_fma(Wreg[(r*4+q)*4+3], hh, acc3);
            }
        }

        // out[b][t-1][o] = Wout . h_t
        op = dpp_add<0xB1>(op);  op = dpp_add<0x4E>(op);
        op = dpp_add<0x124>(op); op = dpp_add<0x128>(op);
        op = dpp_add<0x142>(op);
        if (t > 0 && ovalid && ((lane & 31) == 31))
            orow[(size_t)(t-1)*50 + oidx] = op;

        // ---- u for my row (x_t is wave-uniform -> s_loads)
        float u = 0.f;
        #pragma unroll
        for (int k = 0; k < 25; ++k) u = fmaf(WinR[k], xrow[t*25 + k], u);

        // ---- FULL 32-lane reduce of 8 row partials (total lands in lanes 16..31)
        float ar[8] = {acc0[0],acc0[1],acc1[0],acc1[1],acc2[0],acc2[1],acc3[0],acc3[1]};
        #pragma unroll
        for (int j = 0; j < 8; ++j) {
            ar[j] = dpp_add<0xB1>(ar[j]);
            ar[j] = dpp_add<0x4E>(ar[j]);
            ar[j] = dpp_add<0x124>(ar[j]);
            ar[j] = dpp_add<0x128>(ar[j]);
            ar[j] = dpp_add<0x142>(ar[j]);
        }

        // ---- finalize rows i0+(ct&7): lanes ct in [16,24)
        if (fin) {
            const int j = ct & 7;
            float y = ar[0];
            if (j == 1) y = ar[1];
            if (j == 2) y = ar[2];
            if (j == 3) y = ar[3];
            if (j == 4) y = ar[4];
            if (j == 5) y = ar[5];
            if (j == 6) y = ar[6];
            if (j == 7) y = ar[7];
            const float z  = u + y;
            const float e  = __expf(2.f * z);
            const float th = 1.f - 2.f * __builtin_amdgcn_rcpf(e + 1.f);  // tanh
            holdv = 0.5f * holdv + 0.5f * th;
            hperm[npar][permidx(myrow)] = holdv;          // own slice via LDS
            store_coh8(&HfN[myrow*2], holdv, want);       // fire-and-forget
        }

        // ---- comm wave: speculative tagged fetch of 3 remote slices
        if (wv == 0) {
            const float* p0 = HfN + (s0*256 + lane*4);
            const float* p1 = HfN + (s1*256 + lane*4);
            const float* p2 = HfN + (s2*256 + lane*4);
            v4f d0, d1, d2;
            load3_coh16(p0, p1, p2, d0, d1, d2);
            while (__float_as_int(d0.y) != want || __float_as_int(d0.w) != want)
                d0 = load_coh16(p0);
            while (__float_as_int(d1.y) != want || __float_as_int(d1.w) != want)
                d1 = load_coh16(p1);
            while (__float_as_int(d2.y) != want || __float_as_int(d2.w) != want)
                d2 = load_coh16(p2);
            const int c0 = s0*128 + 2*lane, c1 = s1*128 + 2*lane, c2 = s2*128 + 2*lane;
            hperm[npar][permidx(c0)]     = d0.x;
            hperm[npar][permidx(c0 + 1)] = d0.z;
            hperm[npar][permidx(c1)]     = d1.x;
            hperm[npar][permidx(c1 + 1)] = d1.z;
            hperm[npar][permidx(c2)]     = d2.x;
            hperm[npar][permidx(c2 + 1)] = d2.z;
        }
        __syncthreads();   // the ONLY barrier per step
    }

    // epilogue: out[b][2047] from h_2048 (in hperm[0], since 2048&1==0)
    {
        float op = 0.f;
        #pragma unroll
        for (int r = 0; r < 4; ++r) {
            v4f hv = *(const v4f*)&hperm[0][r*128 + ct*4];
            #pragma unroll
            for (int q = 0; q < 4; ++q) op = fmaf(WoutR[r*4+q], hv[q], op);
        }
        op = dpp_add<0xB1>(op);  op = dpp_add<0x4E>(op);
        op = dpp_add<0x124>(op); op = dpp_add<0x128>(op);
        op = dpp_add<0x142>(op);
        if (ovalid && ((lane & 31) == 31))
            orow[(size_t)2047*50 + oidx] = op;
    }
}

extern "C" void kernel_launch(void* const* d_in, const int* in_sizes, int n_in,
                              void* d_out, int out_size, void* d_ws, size_t ws_size,
                              hipStream_t stream)
{
    (void)in_sizes; (void)n_in; (void)out_size; (void)ws_size;
    const float* x    = (const float*)d_in[0];
    const float* Win  = (const float*)d_in[1];
    const float* W    = (const float*)d_in[2];
    const float* Wout = (const float*)d_in[3];
    float* out = (float*)d_out;
    float* Hf  = (float*)d_ws;   // tagged state: [2][64][512] x {h,tag} = 512 KB
    esn_kernel<<<dim3(256), dim3(512), 0, stream>>>(x, Win, W, Wout, out, Hf);
}

// Round 8
// 2788.329 us; speedup vs baseline: 14.4188x; 1.4314x over previous
//
#include <hip/hip_runtime.h>
#include <math.h>

// ESN: B=64, T=2048, I=25, R=512, O=50, alpha=0.5
// 256 blocks x 512 threads; block=(g,b): b=blk&63, g=blk>>6 owns rows
// [g*128,(g+1)*128). W slice [128x512] fp32 in regs. Seqlock-tagged h pairs
// {h, tag=t+1} (8B single-copy atomic), double-buffered by step parity.
// R8 = R5 protocol + two hang-proof additions:
//  - stores ALWAYS sc0 sc1 (system scope, R5-proven visible everywhere).
//  - comm wave tries sc0-only loads (same-XCD L2 hit ~250cy vs IC ~900cy);
//    a STICKY wave-uniform watchdog (64 retries) falls back to sc0 sc1 loads
//    if the fast path never delivers (stale L2 line or cross-XCD quad).
//    Watchdog IS the XCD-mapping detector -> no handshake, no getreg, no
//    extra workspace (R6/R7 hangs traced to exactly that machinery: +2KB
//    beyond the 512KB ws, hwreg symbol, un-fallback-able sc0 spins).
//  - op-DPP/orow/u_next moved between publish and first poll so the
//    speculative load stops losing the race against a store issued 10cy
//    earlier (R5 always paid one extra round trip).
// ws usage: EXACTLY 512 KB (Hf only), same as passing R5.

typedef float v2f __attribute__((ext_vector_type(2)));
typedef float v4f __attribute__((ext_vector_type(4)));

template<int CTRL>
__device__ __forceinline__ float dpp_add(float x) {
    int y = __builtin_amdgcn_update_dpp(0, __float_as_int(x), CTRL, 0xF, 0xF, false);
    return x + __int_as_float(y);
}
// 0xB1 quad_perm[1,0,3,2], 0x4E quad_perm[2,3,0,1], 0x124 row_ror:4,
// 0x128 row_ror:8, 0x142 row_bcast15

__device__ __forceinline__ void store_ic8(float* p, float h, int tag) {
    v2f v; v[0] = h; v[1] = __int_as_float(tag);
    asm volatile("global_store_dwordx2 %0, %1, off sc0 sc1"
                 :: "v"(p), "v"(v) : "memory");
}
// 3 tagged 16B loads + wait in ONE asm block (R5-proven codegen shape)
__device__ __forceinline__ void load3_ic(const float* p0, const float* p1,
                                         const float* p2, v4f& a, v4f& b, v4f& c) {
    asm volatile("global_load_dwordx4 %0, %3, off sc0 sc1\n\t"
                 "global_load_dwordx4 %1, %4, off sc0 sc1\n\t"
                 "global_load_dwordx4 %2, %5, off sc0 sc1\n\t"
                 "s_waitcnt vmcnt(0)"
                 : "=&v"(a), "=&v"(b), "=&v"(c)
                 : "v"(p0), "v"(p1), "v"(p2) : "memory");
}
__device__ __forceinline__ void load3_l2(const float* p0, const float* p1,
                                         const float* p2, v4f& a, v4f& b, v4f& c) {
    asm volatile("global_load_dwordx4 %0, %3, off sc0\n\t"
                 "global_load_dwordx4 %1, %4, off sc0\n\t"
                 "global_load_dwordx4 %2, %5, off sc0\n\t"
                 "s_waitcnt vmcnt(0)"
                 : "=&v"(a), "=&v"(b), "=&v"(c)
                 : "v"(p0), "v"(p1), "v"(p2) : "memory");
}

__device__ __forceinline__ int permidx(int c) {
    return (c >> 7) * 128 + (c & 31) * 4 + ((c >> 5) & 3);
}

#define TAGS_BAD (__any((__float_as_int(d0.y) != want) | (__float_as_int(d0.w) != want) | \
                        (__float_as_int(d1.y) != want) | (__float_as_int(d1.w) != want) | \
                        (__float_as_int(d2.y) != want) | (__float_as_int(d2.w) != want)))

__global__ void __launch_bounds__(512, 2)
esn_kernel(const float* __restrict__ x, const float* __restrict__ Win,
           const float* __restrict__ W, const float* __restrict__ Wout,
           float* __restrict__ out, float* __restrict__ Hf)
{
    const int b    = blockIdx.x & 63;
    const int g    = blockIdx.x >> 6;
    const int tid  = threadIdx.x;
    const int rt   = tid >> 5;      // row-tile 0..15 (8 rows each)
    const int ct   = tid & 31;      // col phase
    const int lane = tid & 63;
    const int wv   = tid >> 6;      // wave 0..7
    const int hw   = rt & 1;

    __shared__ __align__(16) float hperm[2][512];

    // ---- W slice -> registers
    v2f Wreg[64];
    {
        const int i0 = g*128 + rt*8;
        #pragma unroll
        for (int r = 0; r < 4; ++r)
        #pragma unroll
        for (int q = 0; q < 4; ++q) {
            const float* wp = W + (r*128 + q*32 + ct);
            #pragma unroll
            for (int p = 0; p < 4; ++p) {
                v2f w;
                w[0] = wp[(size_t)(i0 + 2*p    ) * 512];
                w[1] = wp[(size_t)(i0 + 2*p + 1) * 512];
                Wreg[(r*4+q)*4 + p] = w;
            }
        }
    }

    // ---- Win row for this lane's finalize row i0+(ct&7)
    const int myrow = g*128 + rt*8 + (ct & 7);
    float WinR[25];
    #pragma unroll
    for (int k = 0; k < 25; ++k) WinR[k] = Win[myrow*25 + k];

    // ---- Wout fragment
    const int obase = g*13;
    const int ocnt  = (g == 3) ? 11 : 13;
    const int oloc  = 2*wv + hw;
    const bool ovalid = (oloc < ocnt);
    const int oidx  = obase + (ovalid ? oloc : 0);
    float WoutR[16];
    #pragma unroll
    for (int r = 0; r < 4; ++r)
    #pragma unroll
    for (int q = 0; q < 4; ++q)
        WoutR[r*4+q] = ovalid ? Wout[oidx*512 + r*128 + q*32 + ct] : 0.f;

    hperm[0][tid] = 0.f;        // h_0 = 0
    float holdv = 0.f;
    const bool fin = (ct >= 16) & (ct < 24);

    const float* xrow = x   + (size_t)b * 2048 * 25;
    float*       orow = out + (size_t)b * 2048 * 50;
    float* HfB0 = Hf + (size_t)b * 1024;              // par-0 base (pairs)
    const int s0 = (g+1)&3, s1 = (g+2)&3, s2 = (g+3)&3;

    bool fast = true;           // sticky fast-path flag (comm wave only)

    __syncthreads();

    // u for t=0
    float u = 0.f;
    #pragma unroll
    for (int k = 0; k < 25; ++k) u = fmaf(WinR[k], xrow[k], u);

    for (int t = 0; t < 2048; ++t) {
        const int par  = t & 1;
        const int npar = par ^ 1;
        const int want = t + 1;
        float* HfN = HfB0 + (size_t)npar * 64 * 1024;

        // ---- matvec on h_t + fused output-projection partial
        v2f acc0 = {0.f,0.f}, acc1 = {0.f,0.f}, acc2 = {0.f,0.f}, acc3 = {0.f,0.f};
        float op = 0.f;
        #pragma unroll
        for (int r = 0; r < 4; ++r) {
            v4f hv = *(const v4f*)&hperm[par][r*128 + ct*4];
            #pragma unroll
            for (int q = 0; q < 4; ++q) {
                const float hs = hv[q];
                op = fmaf(WoutR[r*4+q], hs, op);
                v2f hh = {hs, hs};
                acc0 = __builtin_elementwise_fma(Wreg[(r*4+q)*4+0], hh, acc0);
                acc1 = __builtin_elementwise_fma(Wreg[(r*4+q)*4+1], hh, acc1);
                acc2 = __builtin_elementwise_fma(Wreg[(r*4+q)*4+2], hh, acc2);
                acc3 = __builtin_elementwise_fma(Wreg[(r*4+q)*4+3], hh, acc3);
            }
        }

        // ---- FULL 32-lane reduce of 8 row partials (totals land in lanes 16..31)
        float ar[8] = {acc0[0],acc0[1],acc1[0],acc1[1],acc2[0],acc2[1],acc3[0],acc3[1]};
        #pragma unroll
        for (int j = 0; j < 8; ++j) {
            ar[j] = dpp_add<0xB1>(ar[j]);
            ar[j] = dpp_add<0x4E>(ar[j]);
            ar[j] = dpp_add<0x124>(ar[j]);
            ar[j] = dpp_add<0x128>(ar[j]);
            ar[j] = dpp_add<0x142>(ar[j]);
        }

        // ---- finalize rows i0+(ct&7) (lanes ct in [16,24)), publish ASAP
        if (fin) {
            const int j = ct & 7;
            float y = ar[0];
            if (j == 1) y = ar[1];
            if (j == 2) y = ar[2];
            if (j == 3) y = ar[3];
            if (j == 4) y = ar[4];
            if (j == 5) y = ar[5];
            if (j == 6) y = ar[6];
            if (j == 7) y = ar[7];
            const float z  = u + y;
            const float e  = __expf(2.f * z);
            const float th = 1.f - 2.f * __builtin_amdgcn_rcpf(e + 1.f);  // tanh
            holdv = 0.5f * holdv + 0.5f * th;
            hperm[npar][permidx(myrow)] = holdv;          // own slice via LDS
            store_ic8(&HfN[myrow*2], holdv, want);        // ALWAYS sc0 sc1
        }

        // ---- filler (delays first poll past the store's landing):
        //      out[b][t-1] projection emit + u_{t+1}
        op = dpp_add<0xB1>(op);  op = dpp_add<0x4E>(op);
        op = dpp_add<0x124>(op); op = dpp_add<0x128>(op);
        op = dpp_add<0x142>(op);
        if (t > 0 && ovalid && ((lane & 31) == 31))
            orow[(size_t)(t-1)*50 + oidx] = op;
        {
            const int tt = (t < 2047) ? t + 1 : 2047;
            float un = 0.f;
            #pragma unroll
            for (int k = 0; k < 25; ++k) un = fmaf(WinR[k], xrow[tt*25 + k], un);
            u = un;
        }

        // ---- comm wave: tagged fetch of 3 remote slices
        if (wv == 0) {
            const float* p0 = HfN + (s0*256 + lane*4);
            const float* p1 = HfN + (s1*256 + lane*4);
            const float* p2 = HfN + (s2*256 + lane*4);
            v4f d0, d1, d2;
            if (fast) {
                int tries = 0;
                do { load3_l2(p0, p1, p2, d0, d1, d2); } while (TAGS_BAD && ++tries < 64);
                if (TAGS_BAD) fast = false;   // sticky fallback: fast path dead
            }
            if (!fast) {
                do { load3_ic(p0, p1, p2, d0, d1, d2); } while (TAGS_BAD);
            }
            const int c0 = s0*128 + 2*lane, c1 = s1*128 + 2*lane, c2 = s2*128 + 2*lane;
            hperm[npar][permidx(c0)]     = d0.x;
            hperm[npar][permidx(c0 + 1)] = d0.z;
            hperm[npar][permidx(c1)]     = d1.x;
            hperm[npar][permidx(c1 + 1)] = d1.z;
            hperm[npar][permidx(c2)]     = d2.x;
            hperm[npar][permidx(c2 + 1)] = d2.z;
        }
        __syncthreads();   // the ONLY barrier per step
    }

    // epilogue: out[b][2047] from h_2048 (in hperm[0])
    {
        float op = 0.f;
        #pragma unroll
        for (int r = 0; r < 4; ++r) {
            v4f hv = *(const v4f*)&hperm[0][r*128 + ct*4];
            #pragma unroll
            for (int q = 0; q < 4; ++q) op = fmaf(WoutR[r*4+q], hv[q], op);
        }
        op = dpp_add<0xB1>(op);  op = dpp_add<0x4E>(op);
        op = dpp_add<0x124>(op); op = dpp_add<0x128>(op);
        op = dpp_add<0x142>(op);
        if (ovalid && ((lane & 31) == 31))
            orow[(size_t)2047*50 + oidx] = op;
    }
}

extern "C" void kernel_launch(void* const* d_in, const int* in_sizes, int n_in,
                              void* d_out, int out_size, void* d_ws, size_t ws_size,
                              hipStream_t stream)
{
    (void)in_sizes; (void)n_in; (void)out_size; (void)ws_size;
    const float* x    = (const float*)d_in[0];
    const float* Win  = (const float*)d_in[1];
    const float* W    = (const float*)d_in[2];
    const float* Wout = (const float*)d_in[3];
    float* out = (float*)d_out;
    float* Hf  = (float*)d_ws;   // [2][64][512] x {h,tag} = 512 KB (same as R5)
    esn_kernel<<<dim3(256), dim3(512), 0, stream>>>(x, Win, W, Wout, out, Hf);
}